// Round 3
// baseline (872.226 us; speedup 1.0000x reference)
//
#include <hip/hip_runtime.h>
#include <hip/hip_bf16.h>

#define BB 4
#define SS 1024
#define HH 16
#define DK 64
#define DM 1024
#define MM (BB * SS)  // 4096

typedef __attribute__((ext_vector_type(8))) short bh8_t;  // 8 bf16 (4 VGPRs)
typedef __attribute__((ext_vector_type(4))) float f4_t;   // 4 fp32

#define MFMA(a, b, c) __builtin_amdgcn_mfma_f32_16x16x32_bf16(a, b, c, 0, 0, 0)

// fp32 -> bf16 (RNE) raw bits
__device__ __forceinline__ short f2bf(float f) {
    unsigned u = __builtin_bit_cast(unsigned, f);
    u = (u + 0x7FFFu + ((u >> 16) & 1u)) >> 16;
    return (short)u;
}
__device__ __forceinline__ float bf2f(short h) {
    unsigned u = ((unsigned)(unsigned short)h) << 16;
    return __builtin_bit_cast(float, u);
}

// T5 relative position bucket (bidirectional); rel = k - q
__device__ __forceinline__ int rel_bucket(int rel) {
    int n = -rel;
    int ret = 0;
    if (n < 0) { ret = 16; n = -n; }
    int v;
    if (n < 8) {
        v = n;
    } else {
        float t = logf((float)n * 0.125f) / 2.7725887298583984f * 8.0f;
        v = 8 + (int)t;
        if (v > 15) v = 15;
    }
    return ret + v;
}

// ---------------------------------------------------------------------------
// Pre-pass: one-time fp32 -> bf16 (split hi/lo for X, Wq, Wk; hi-only Wv, Wo).
// Linear float4 ranges: [0,4M)=X, [4M,5M)=Wq, [5M,6M)=Wk, [6M,7M)=Wv, [7M,8M)=Wo
// ---------------------------------------------------------------------------
__global__ __launch_bounds__(256)
void k_cvt(const float* __restrict__ X, const float* __restrict__ Wq,
           const float* __restrict__ Wk, const float* __restrict__ Wv,
           const float* __restrict__ Wo,
           short* __restrict__ Xh, short* __restrict__ Xl,
           short* __restrict__ Wqh, short* __restrict__ Wql,
           short* __restrict__ Wkh, short* __restrict__ Wkl,
           short* __restrict__ Wvh, short* __restrict__ Woh) {
    const long base = ((long)blockIdx.x * 256 + threadIdx.x) * 4;
    const float* src;
    short* dh;
    short* dl = nullptr;
    long off;
    if (base < 4194304L)      { src = X;  dh = Xh;  dl = Xl;  off = base; }
    else if (base < 5242880L) { src = Wq; dh = Wqh; dl = Wql; off = base - 4194304L; }
    else if (base < 6291456L) { src = Wk; dh = Wkh; dl = Wkl; off = base - 5242880L; }
    else if (base < 7340032L) { src = Wv; dh = Wvh;           off = base - 6291456L; }
    else                      { src = Wo; dh = Woh;           off = base - 7340032L; }
    float4 v = *(const float4*)(src + off);
    short4 h;
    h.x = f2bf(v.x); h.y = f2bf(v.y); h.z = f2bf(v.z); h.w = f2bf(v.w);
    *(short4*)(dh + off) = h;
    if (dl) {
        short4 l;
        l.x = f2bf(v.x - bf2f(h.x)); l.y = f2bf(v.y - bf2f(h.y));
        l.z = f2bf(v.z - bf2f(h.z)); l.w = f2bf(v.w - bf2f(h.w));
        *(short4*)(dl + off) = l;
    }
}

// ---------------------------------------------------------------------------
// Q/K projection from pre-split operands (3-MFMA split product).
// 128x128 tile, BK=32, 256 thr = 4 waves (2x2 of 64x64). Out [B,H,S,DK] split.
// ---------------------------------------------------------------------------
__global__ __launch_bounds__(256)
void k_proj_qk(const short* __restrict__ Xh, const short* __restrict__ Xl,
               const short* __restrict__ Wqh, const short* __restrict__ Wql,
               const short* __restrict__ Wkh, const short* __restrict__ Wkl,
               short* __restrict__ Qh, short* __restrict__ Ql,
               short* __restrict__ Kh, short* __restrict__ Kl) {
    const int z = blockIdx.z;
    const short* Wh_ = z ? Wkh : Wqh;
    const short* Wl_ = z ? Wkl : Wql;
    short* Oh = z ? Kh : Qh;
    short* Ol = z ? Kl : Ql;

    __shared__ short Ah[128][40], Al[128][40], Bh[128][40], Bl[128][40];

    const int tid = threadIdx.x;
    const int m0 = blockIdx.y * 128, n0 = blockIdx.x * 128;
    const int wave = tid >> 6, lane = tid & 63;
    const int quad = lane >> 4, lm = lane & 15;
    const int wm = (wave >> 1) * 64, wn = (wave & 1) * 64;
    const int r = tid >> 1, sg = (tid & 1) * 16;

    f4_t acc[4][4];
#pragma unroll
    for (int i = 0; i < 4; ++i)
#pragma unroll
        for (int j = 0; j < 4; ++j) acc[i][j] = (f4_t){0.f, 0.f, 0.f, 0.f};

    for (int k0 = 0; k0 < DM; k0 += 32) {
        const size_t ao = (size_t)(m0 + r) * DM + k0 + sg;
        const size_t bo = (size_t)(n0 + r) * DM + k0 + sg;
        uint4 ah0 = *(const uint4*)(Xh + ao), ah1 = *(const uint4*)(Xh + ao + 8);
        uint4 al0 = *(const uint4*)(Xl + ao), al1 = *(const uint4*)(Xl + ao + 8);
        uint4 bh0 = *(const uint4*)(Wh_ + bo), bh1 = *(const uint4*)(Wh_ + bo + 8);
        uint4 bl0 = *(const uint4*)(Wl_ + bo), bl1 = *(const uint4*)(Wl_ + bo + 8);
        __syncthreads();
        *(uint4*)&Ah[r][sg] = ah0; *(uint4*)&Ah[r][sg + 8] = ah1;
        *(uint4*)&Al[r][sg] = al0; *(uint4*)&Al[r][sg + 8] = al1;
        *(uint4*)&Bh[r][sg] = bh0; *(uint4*)&Bh[r][sg + 8] = bh1;
        *(uint4*)&Bl[r][sg] = bl0; *(uint4*)&Bl[r][sg + 8] = bl1;
        __syncthreads();

        bh8_t ah[4], al[4];
#pragma unroll
        for (int i = 0; i < 4; ++i) {
            ah[i] = *(const bh8_t*)&Ah[wm + i * 16 + lm][quad * 8];
            al[i] = *(const bh8_t*)&Al[wm + i * 16 + lm][quad * 8];
        }
#pragma unroll
        for (int j = 0; j < 4; ++j) {
            bh8_t bhj = *(const bh8_t*)&Bh[wn + j * 16 + lm][quad * 8];
            bh8_t blj = *(const bh8_t*)&Bl[wn + j * 16 + lm][quad * 8];
#pragma unroll
            for (int i = 0; i < 4; ++i) {
                acc[i][j] = MFMA(al[i], bhj, acc[i][j]);
                acc[i][j] = MFMA(ah[i], blj, acc[i][j]);
                acc[i][j] = MFMA(ah[i], bhj, acc[i][j]);
            }
        }
    }

#pragma unroll
    for (int i = 0; i < 4; ++i)
#pragma unroll
        for (int j = 0; j < 4; ++j)
#pragma unroll
            for (int g = 0; g < 4; ++g) {
                const int row = m0 + wm + i * 16 + quad * 4 + g;
                const int col = n0 + wn + j * 16 + lm;
                const int b = row >> 10, s = row & 1023;
                const int hd = col >> 6, dk = col & 63;
                const float v = acc[i][j][g];
                const short vh = f2bf(v);
                const short vl = f2bf(v - bf2f(vh));
                const size_t o = ((size_t)((b * HH + hd) * SS + s)) * DK + dk;
                Oh[o] = vh;
                Ol[o] = vl;
            }
}

// ---------------------------------------------------------------------------
// V projection (single bf16); writes transposed Vt[bh][dk][s].
// ---------------------------------------------------------------------------
__global__ __launch_bounds__(256)
void k_proj_v(const short* __restrict__ Xh, const short* __restrict__ Wvh,
              short* __restrict__ Vt) {
    __shared__ short As[128][40], Bs[128][40];

    const int tid = threadIdx.x;
    const int m0 = blockIdx.y * 128, n0 = blockIdx.x * 128;
    const int wave = tid >> 6, lane = tid & 63;
    const int quad = lane >> 4, lm = lane & 15;
    const int wm = (wave >> 1) * 64, wn = (wave & 1) * 64;
    const int r = tid >> 1, sg = (tid & 1) * 16;

    f4_t acc[4][4];
#pragma unroll
    for (int i = 0; i < 4; ++i)
#pragma unroll
        for (int j = 0; j < 4; ++j) acc[i][j] = (f4_t){0.f, 0.f, 0.f, 0.f};

    for (int k0 = 0; k0 < DM; k0 += 32) {
        const size_t ao = (size_t)(m0 + r) * DM + k0 + sg;
        const size_t bo = (size_t)(n0 + r) * DM + k0 + sg;
        uint4 a0 = *(const uint4*)(Xh + ao), a1 = *(const uint4*)(Xh + ao + 8);
        uint4 b0 = *(const uint4*)(Wvh + bo), b1 = *(const uint4*)(Wvh + bo + 8);
        __syncthreads();
        *(uint4*)&As[r][sg] = a0; *(uint4*)&As[r][sg + 8] = a1;
        *(uint4*)&Bs[r][sg] = b0; *(uint4*)&Bs[r][sg + 8] = b1;
        __syncthreads();

        bh8_t ah[4];
#pragma unroll
        for (int i = 0; i < 4; ++i)
            ah[i] = *(const bh8_t*)&As[wm + i * 16 + lm][quad * 8];
#pragma unroll
        for (int j = 0; j < 4; ++j) {
            bh8_t bhj = *(const bh8_t*)&Bs[wn + j * 16 + lm][quad * 8];
#pragma unroll
            for (int i = 0; i < 4; ++i) acc[i][j] = MFMA(ah[i], bhj, acc[i][j]);
        }
    }

#pragma unroll
    for (int i = 0; i < 4; ++i)
#pragma unroll
        for (int j = 0; j < 4; ++j)
#pragma unroll
            for (int g = 0; g < 4; ++g) {
                const int row = m0 + wm + i * 16 + quad * 4 + g;
                const int col = n0 + wn + j * 16 + lm;
                const int b = row >> 10, s = row & 1023;
                const int hd = col >> 6, dk = col & 63;
                Vt[((size_t)((b * HH + hd) * DK + dk)) * SS + s] = f2bf(acc[i][j][g]);
            }
}

// ---------------------------------------------------------------------------
// Fused scores + softmax. Block = 16 q-rows x full 1024 k for one (b,h).
// Waves split k (wave w owns cols w*32 + t*16 within each 128-chunk).
// Split-bf16 QK^T; bias+mask; in-register softmax with shfl+LDS reductions;
// writes normalized attn_weights P once.
// ---------------------------------------------------------------------------
__global__ __launch_bounds__(256)
void k_ssm(const short* __restrict__ Qh, const short* __restrict__ Ql,
           const short* __restrict__ Kh, const short* __restrict__ Kl,
           const int* __restrict__ mask, const float* __restrict__ rb,
           float* __restrict__ P) {
    __shared__ short Qhs[16][72], Qls[16][72];
    __shared__ short Khs[128][72], Kls[128][72];
    __shared__ float biasS[1040];
    __shared__ int maskS[1024];
    __shared__ float red[4][16];

    const int bh = blockIdx.y, b = bh >> 4, h = bh & 15;
    const int q0 = blockIdx.x * 16;
    const int tid = threadIdx.x;
    const int wave = tid >> 6, lane = tid & 63;
    const int quad = lane >> 4, lm = lane & 15;

    if (tid < 128) {
        const int r = tid >> 3, sg = (tid & 7) * 8;
        const size_t qo = ((size_t)bh * SS + q0 + r) * DK + sg;
        *(uint4*)&Qhs[r][sg] = *(const uint4*)(Qh + qo);
        *(uint4*)&Qls[r][sg] = *(const uint4*)(Ql + qo);
    }
    for (int i = tid; i < 1039; i += 256)
        biasS[i] = rb[rel_bucket(i - 15 - q0) * HH + h];
    *(int4*)&maskS[tid * 4] = *(const int4*)(mask + b * SS + tid * 4);
    __syncthreads();

    bh8_t qh[2], ql[2];
#pragma unroll
    for (int ks = 0; ks < 2; ++ks) {
        qh[ks] = *(const bh8_t*)&Qhs[lm][ks * 32 + quad * 8];
        ql[ks] = *(const bh8_t*)&Qls[lm][ks * 32 + quad * 8];
    }

    f4_t acc[16];
#pragma unroll
    for (int i = 0; i < 16; ++i) acc[i] = (f4_t){0.f, 0.f, 0.f, 0.f};

    const int rK = tid >> 1, sgK = (tid & 1) * 32;
#pragma unroll
    for (int c = 0; c < 8; ++c) {
        const int kc = c * 128;
        uint4 vh[4], vl[4];
        const size_t ko = ((size_t)bh * SS + kc + rK) * DK + sgK;
#pragma unroll
        for (int u = 0; u < 4; ++u) {
            vh[u] = *(const uint4*)(Kh + ko + u * 8);
            vl[u] = *(const uint4*)(Kl + ko + u * 8);
        }
        __syncthreads();
#pragma unroll
        for (int u = 0; u < 4; ++u) {
            *(uint4*)&Khs[rK][sgK + u * 8] = vh[u];
            *(uint4*)&Kls[rK][sgK + u * 8] = vl[u];
        }
        __syncthreads();

#pragma unroll
        for (int t = 0; t < 2; ++t) {
            const int col0 = wave * 32 + t * 16;
            const int ai = c * 2 + t;
#pragma unroll
            for (int ks = 0; ks < 2; ++ks) {
                bh8_t kbh = *(const bh8_t*)&Khs[col0 + lm][ks * 32 + quad * 8];
                bh8_t kbl = *(const bh8_t*)&Kls[col0 + lm][ks * 32 + quad * 8];
                acc[ai] = MFMA(ql[ks], kbh, acc[ai]);
                acc[ai] = MFMA(qh[ks], kbl, acc[ai]);
                acc[ai] = MFMA(qh[ks], kbh, acc[ai]);
            }
        }
    }

    // scale + bias + mask (in place)
#pragma unroll
    for (int ai = 0; ai < 16; ++ai) {
        const int colg = (ai >> 1) * 128 + wave * 32 + (ai & 1) * 16 + lm;
        const int msk = maskS[colg];
#pragma unroll
        for (int g = 0; g < 4; ++g) {
            const int row = quad * 4 + g;
            float s = acc[ai][g] * 0.125f + biasS[colg - row + 15];
            acc[ai][g] = (msk == 0) ? -1e9f : s;
        }
    }

    // row max (per lane -> lm lanes -> waves)
    float m[4];
#pragma unroll
    for (int g = 0; g < 4; ++g) {
        m[g] = acc[0][g];
#pragma unroll
        for (int ai = 1; ai < 16; ++ai) m[g] = fmaxf(m[g], acc[ai][g]);
#pragma unroll
        for (int off = 1; off < 16; off <<= 1)
            m[g] = fmaxf(m[g], __shfl_xor(m[g], off, 64));
    }
    if (lm == 0)
#pragma unroll
        for (int g = 0; g < 4; ++g) red[wave][quad * 4 + g] = m[g];
    __syncthreads();
#pragma unroll
    for (int g = 0; g < 4; ++g)
        m[g] = fmaxf(fmaxf(red[0][quad * 4 + g], red[1][quad * 4 + g]),
                     fmaxf(red[2][quad * 4 + g], red[3][quad * 4 + g]));
    __syncthreads();

    // exp + row sum
    float sum[4] = {0.f, 0.f, 0.f, 0.f};
#pragma unroll
    for (int ai = 0; ai < 16; ++ai)
#pragma unroll
        for (int g = 0; g < 4; ++g) {
            const float e = __expf(acc[ai][g] - m[g]);
            acc[ai][g] = e;
            sum[g] += e;
        }
#pragma unroll
    for (int g = 0; g < 4; ++g)
#pragma unroll
        for (int off = 1; off < 16; off <<= 1)
            sum[g] += __shfl_xor(sum[g], off, 64);
    if (lm == 0)
#pragma unroll
        for (int g = 0; g < 4; ++g) red[wave][quad * 4 + g] = sum[g];
    __syncthreads();
    float inv[4];
#pragma unroll
    for (int g = 0; g < 4; ++g)
        inv[g] = 1.0f / (red[0][quad * 4 + g] + red[1][quad * 4 + g] +
                         red[2][quad * 4 + g] + red[3][quad * 4 + g]);

    // write normalized attn_weights
#pragma unroll
    for (int ai = 0; ai < 16; ++ai) {
        const int colg = (ai >> 1) * 128 + wave * 32 + (ai & 1) * 16 + lm;
#pragma unroll
        for (int g = 0; g < 4; ++g)
            P[((size_t)bh * SS + q0 + quad * 4 + g) * SS + colg] = acc[ai][g] * inv[g];
    }
}

// ---------------------------------------------------------------------------
// AO = P @ V per (bh). P fp32 -> bf16 inline (read once); Vt pre-transposed.
// ---------------------------------------------------------------------------
__global__ __launch_bounds__(256)
void k_pv(const float* __restrict__ P, const short* __restrict__ Vt,
          short* __restrict__ AO) {
    __shared__ short As[128][40];
    __shared__ short Bs[64][40];

    const int bh = blockIdx.y, b = bh >> 4, hd = bh & 15;
    const int q0 = blockIdx.x * 128;
    const int tid = threadIdx.x;
    const int wave = tid >> 6, lane = tid & 63;
    const int quad = lane >> 4, lm = lane & 15;
    const int wm = wave * 32;
    const int rA = tid >> 1, sgA = (tid & 1) * 16;
    const int rB = tid >> 2, sgB = (tid & 3) * 8;

    f4_t acc[2][4];
#pragma unroll
    for (int i = 0; i < 2; ++i)
#pragma unroll
        for (int j = 0; j < 4; ++j) acc[i][j] = (f4_t){0.f, 0.f, 0.f, 0.f};

    for (int k0 = 0; k0 < SS; k0 += 32) {
        f4_t pr[4];
#pragma unroll
        for (int u = 0; u < 4; ++u)
            pr[u] = *(const f4_t*)(P + ((size_t)bh * SS + q0 + rA) * SS + k0 + sgA + u * 4);
        uint4 vb = *(const uint4*)(Vt + ((size_t)bh * DK + rB) * SS + k0 + sgB);
        __syncthreads();
#pragma unroll
        for (int u = 0; u < 4; ++u) {
            short4 hh;
            hh.x = f2bf(pr[u][0]); hh.y = f2bf(pr[u][1]);
            hh.z = f2bf(pr[u][2]); hh.w = f2bf(pr[u][3]);
            *(short4*)&As[rA][sgA + u * 4] = hh;
        }
        *(uint4*)&Bs[rB][sgB] = vb;
        __syncthreads();

        bh8_t af0 = *(const bh8_t*)&As[wm + lm][quad * 8];
        bh8_t af1 = *(const bh8_t*)&As[wm + 16 + lm][quad * 8];
#pragma unroll
        for (int j = 0; j < 4; ++j) {
            bh8_t bf = *(const bh8_t*)&Bs[j * 16 + lm][quad * 8];
            acc[0][j] = MFMA(af0, bf, acc[0][j]);
            acc[1][j] = MFMA(af1, bf, acc[1][j]);
        }
    }

#pragma unroll
    for (int i = 0; i < 2; ++i)
#pragma unroll
        for (int j = 0; j < 4; ++j)
#pragma unroll
            for (int g = 0; g < 4; ++g) {
                const int s = q0 + wm + i * 16 + quad * 4 + g;
                const int dk = j * 16 + lm;
                AO[((size_t)(b * SS + s)) * DM + hd * DK + dk] = f2bf(acc[i][j][g]);
            }
}

// ---------------------------------------------------------------------------
// out = AO(bf16) @ Woh^T (pre-converted bf16). 128x128 tile, fp32 out.
// ---------------------------------------------------------------------------
__global__ __launch_bounds__(256)
void k_out(const short* __restrict__ A, const short* __restrict__ Woh,
           float* __restrict__ Out) {
    __shared__ short As[128][40], Bs[128][40];

    const int tid = threadIdx.x;
    const int m0 = blockIdx.y * 128, n0 = blockIdx.x * 128;
    const int wave = tid >> 6, lane = tid & 63;
    const int quad = lane >> 4, lm = lane & 15;
    const int wm = (wave >> 1) * 64, wn = (wave & 1) * 64;
    const int r = tid >> 1, sg = (tid & 1) * 16;

    f4_t acc[4][4];
#pragma unroll
    for (int i = 0; i < 4; ++i)
#pragma unroll
        for (int j = 0; j < 4; ++j) acc[i][j] = (f4_t){0.f, 0.f, 0.f, 0.f};

    for (int k0 = 0; k0 < DM; k0 += 32) {
        const size_t ao = (size_t)(m0 + r) * DM + k0 + sg;
        const size_t bo = (size_t)(n0 + r) * DM + k0 + sg;
        uint4 a0 = *(const uint4*)(A + ao), a1 = *(const uint4*)(A + ao + 8);
        uint4 b0 = *(const uint4*)(Woh + bo), b1 = *(const uint4*)(Woh + bo + 8);
        __syncthreads();
        *(uint4*)&As[r][sg] = a0; *(uint4*)&As[r][sg + 8] = a1;
        *(uint4*)&Bs[r][sg] = b0; *(uint4*)&Bs[r][sg + 8] = b1;
        __syncthreads();

        bh8_t ah[4];
#pragma unroll
        for (int i = 0; i < 4; ++i)
            ah[i] = *(const bh8_t*)&As[wm + i * 16 + lm][quad * 8];
#pragma unroll
        for (int j = 0; j < 4; ++j) {
            bh8_t bhj = *(const bh8_t*)&Bs[wn + j * 16 + lm][quad * 8];
#pragma unroll
            for (int i = 0; i < 4; ++i) acc[i][j] = MFMA(ah[i], bhj, acc[i][j]);
        }
    }

#pragma unroll
    for (int i = 0; i < 4; ++i)
#pragma unroll
        for (int j = 0; j < 4; ++j)
#pragma unroll
            for (int g = 0; g < 4; ++g)
                Out[(size_t)(m0 + wm + i * 16 + quad * 4 + g) * DM + n0 + wn + j * 16 + lm] =
                    acc[i][j][g];
}

// ---------------------------------------------------------------------------
extern "C" void kernel_launch(void* const* d_in, const int* in_sizes, int n_in,
                              void* d_out, int out_size, void* d_ws, size_t ws_size,
                              hipStream_t stream) {
    const float* X    = (const float*)d_in[0];
    const int*   mask = (const int*)d_in[1];
    const float* Wq   = (const float*)d_in[2];
    const float* Wk   = (const float*)d_in[3];
    const float* Wv   = (const float*)d_in[4];
    const float* Wo   = (const float*)d_in[5];
    const float* rb   = (const float*)d_in[6];

    float* out = (float*)d_out;
    float* P   = out + (size_t)BB * SS * DM;  // attn_weights region of d_out

    short* ws  = (short*)d_ws;
    short* Qh  = ws;                          // 8 MB  [B,H,S,DK]
    short* Ql  = ws + 4194304L;
    short* Kh  = ws + 8388608L;
    short* Kl  = ws + 12582912L;
    short* Vt  = ws + 16777216L;              // [bh][dk][s]
    short* Xh  = ws + 20971520L;
    short* Xl  = ws + 25165824L;
    short* Wqh = ws + 29360128L;
    short* Wql = ws + 30408704L;
    short* Wkh = ws + 31457280L;
    short* Wkl = ws + 32505856L;
    short* Wvh = ws + 33554432L;
    short* Woh = ws + 34603008L;
    short* AO  = ws;                          // reuse Qh slot (dead after k_ssm)

    k_cvt    <<<8192, 256, 0, stream>>>(X, Wq, Wk, Wv, Wo, Xh, Xl, Wqh, Wql,
                                        Wkh, Wkl, Wvh, Woh);
    k_proj_qk<<<dim3(8, 32, 2), 256, 0, stream>>>(Xh, Xl, Wqh, Wql, Wkh, Wkl,
                                                  Qh, Ql, Kh, Kl);
    k_proj_v <<<dim3(8, 32), 256, 0, stream>>>(Xh, Wvh, Vt);
    k_ssm    <<<dim3(64, 64), 256, 0, stream>>>(Qh, Ql, Kh, Kl, mask, rb, P);
    k_pv     <<<dim3(8, 64), 256, 0, stream>>>(P, Vt, AO);
    k_out    <<<dim3(8, 32), 256, 0, stream>>>(AO, Woh, out);
}